// Round 1
// baseline (97.686 us; speedup 1.0000x reference)
//
#include <hip/hip_runtime.h>
#include <hip/hip_bf16.h>

// 2x2-patch softmax on a [B=16, C=64, H=256, W=256] fp32 tensor.
// Patch = rows (2h,2h+1) x cols (2w,2w+1). Softmax over the 4 values.
//
// Memory-bound: 256 MiB read + 256 MiB write. Strategy: one thread owns a
// float4 (4 consecutive cols) in an even row plus the matching float4 in the
// odd row below it -> 2 complete patches per thread, all accesses coalesced
// 16B/lane.

#define W 256
#define N4_TOTAL (16 * 64 * 128 * 64)  // (B*C*H/2) rowpairs * (W/4) float4/row

__global__ __launch_bounds__(256) void patch_softmax2x2(
    const float* __restrict__ x, float* __restrict__ y) {
    int i = blockIdx.x * blockDim.x + threadIdx.x;
    if (i >= N4_TOTAL) return;

    int r = i >> 6;        // rowpair index: 64 float4 per 256-wide row
    int q = i & 63;        // which float4 within the row
    long base = (long)r * (2 * W) + q * 4;

    float4 t = *reinterpret_cast<const float4*>(x + base);       // even row
    float4 b = *reinterpret_cast<const float4*>(x + base + W);   // odd row

    // Patch A: {t.x, t.y, b.x, b.y}
    float mA = fmaxf(fmaxf(t.x, t.y), fmaxf(b.x, b.y));
    float eA0 = __expf(t.x - mA);
    float eA1 = __expf(t.y - mA);
    float eA2 = __expf(b.x - mA);
    float eA3 = __expf(b.y - mA);
    float invA = 1.0f / (eA0 + eA1 + eA2 + eA3);

    // Patch B: {t.z, t.w, b.z, b.w}
    float mB = fmaxf(fmaxf(t.z, t.w), fmaxf(b.z, b.w));
    float eB0 = __expf(t.z - mB);
    float eB1 = __expf(t.w - mB);
    float eB2 = __expf(b.z - mB);
    float eB3 = __expf(b.w - mB);
    float invB = 1.0f / (eB0 + eB1 + eB2 + eB3);

    float4 ot = make_float4(eA0 * invA, eA1 * invA, eB0 * invB, eB1 * invB);
    float4 ob = make_float4(eA2 * invA, eA3 * invA, eB2 * invB, eB3 * invB);

    *reinterpret_cast<float4*>(y + base) = ot;
    *reinterpret_cast<float4*>(y + base + W) = ob;
}

extern "C" void kernel_launch(void* const* d_in, const int* in_sizes, int n_in,
                              void* d_out, int out_size, void* d_ws, size_t ws_size,
                              hipStream_t stream) {
    const float* x = (const float*)d_in[0];
    float* y = (float*)d_out;
    int blocks = (N4_TOTAL + 255) / 256;  // 32768
    patch_softmax2x2<<<blocks, 256, 0, stream>>>(x, y);
}